// Round 4
// baseline (2464.610 us; speedup 1.0000x reference)
//
#include <hip/hip_runtime.h>
#include <cstdint>

#define BATCH 64
#define SEQ   512
#define DIM   512
#define MTOT  (BATCH*SEQ)   // 32768

// RNN decomposition: 8 column-slices x 32 batch-groups (2 rows each) = 256 wgs
#define CSL 8     // column slices (64 cols each)
#define GRP 32    // batch groups
#define RPG 2     // rows per group
#define SLOT (GRP*RPG*DIM)   // 32768 pairs per parity slot

// ---------------------------------------------------------------------------
// Dual-path transport helpers.
//  A-path: plain store (write-through L1 -> shared L2) / sc0 load (bypass L1,
//          served by L2). Fast when producer+consumer share an XCD — with
//          blockIdx = slice*GRP + grp and round-robin wg->XCD dispatch, all 8
//          wgs of a group land on XCD (grp % 8), so this is the common case.
//  B-path: relaxed agent-scope atomics (sc0+sc1 -> L3) — the R1-proven
//          protocol; guarantees progress under ANY wg->XCD mapping.
// ---------------------------------------------------------------------------
__device__ __forceinline__ void st_plain(unsigned long long* p,
                                         unsigned long long v) {
    asm volatile("global_store_dwordx2 %0, %1, off"
                 :: "v"(p), "v"(v) : "memory");
}

__device__ __forceinline__ void ld2_sc0(const unsigned long long* p0,
                                        const unsigned long long* p1,
                                        unsigned long long& v0,
                                        unsigned long long& v1) {
    asm volatile("global_load_dwordx2 %0, %2, off sc0\n\t"
                 "global_load_dwordx2 %1, %3, off sc0\n\t"
                 "s_waitcnt vmcnt(0)"
                 : "=&v"(v0), "=&v"(v1)
                 : "v"(p0), "v"(p1)
                 : "memory");
}

// ---------------------------------------------------------------------------
// Kernel 0: pack W_hh [c][j] -> Wpk[jb][c] (float4 over j%4); zero BOTH
// tag-pair regions (A and B). Must be re-zeroed EVERY launch: stale tags
// from a previous run (graph replay) would false-match targets 1..511.
// ---------------------------------------------------------------------------
__global__ __launch_bounds__(128) void pack_w(const float* __restrict__ W,
                                              float4* __restrict__ Wpk,
                                              unsigned long long* __restrict__ hpair) {
    const int c  = blockIdx.x;
    const int jb = threadIdx.x;
    const float4 v = *(const float4*)&W[(size_t)c * DIM + 4 * jb];
    Wpk[(size_t)jb * DIM + c] = v;
    const int lin = blockIdx.x * 128 + threadIdx.x;   // 0..65535 == 2*SLOT
    hpair[lin]             = 0ull;   // A region
    hpair[2 * SLOT + lin]  = 0ull;   // B region
}

// ---------------------------------------------------------------------------
// Kernel 1: fused embedding gather + input projection (NT GEMM, fp32)
// ---------------------------------------------------------------------------
__global__ __launch_bounds__(256) void embed_proj(
    const int*   __restrict__ xidx,
    const float* __restrict__ emb,
    const float* __restrict__ W_ih,
    const float* __restrict__ b_ih,
    const float* __restrict__ b_hh,
    float*       __restrict__ xp) {
    __shared__ float As[64][68];  // As[k][m]
    __shared__ float Bs[64][68];  // Bs[k][n]

    const int m0  = blockIdx.x * 64;
    const int n0  = blockIdx.y * 64;
    const int tid = threadIdx.x;

    const int lr = tid >> 4;
    const int lc = (tid & 15) << 2;

    int rows[4];
#pragma unroll
    for (int i = 0; i < 4; i++) rows[i] = xidx[m0 + lr + 16 * i];

    const int tm = (tid & 15) << 2;
    const int tn = (tid >> 4) << 2;

    float acc[4][4];
#pragma unroll
    for (int i = 0; i < 4; i++)
#pragma unroll
        for (int j = 0; j < 4; j++) acc[i][j] = 0.0f;

    for (int k0 = 0; k0 < DIM; k0 += 64) {
#pragma unroll
        for (int i = 0; i < 4; i++) {
            const int rl = lr + 16 * i;
            const float4 a = *(const float4*)&emb[(size_t)rows[i] * DIM + k0 + lc];
            As[lc + 0][rl] = a.x; As[lc + 1][rl] = a.y;
            As[lc + 2][rl] = a.z; As[lc + 3][rl] = a.w;
            const float4 b = *(const float4*)&W_ih[(size_t)(n0 + rl) * DIM + k0 + lc];
            Bs[lc + 0][rl] = b.x; Bs[lc + 1][rl] = b.y;
            Bs[lc + 2][rl] = b.z; Bs[lc + 3][rl] = b.w;
        }
        __syncthreads();
#pragma unroll 8
        for (int kk = 0; kk < 64; kk++) {
            const float4 a = *(const float4*)&As[kk][tm];
            const float4 b = *(const float4*)&Bs[kk][tn];
            acc[0][0] = fmaf(a.x, b.x, acc[0][0]);
            acc[0][1] = fmaf(a.x, b.y, acc[0][1]);
            acc[0][2] = fmaf(a.x, b.z, acc[0][2]);
            acc[0][3] = fmaf(a.x, b.w, acc[0][3]);
            acc[1][0] = fmaf(a.y, b.x, acc[1][0]);
            acc[1][1] = fmaf(a.y, b.y, acc[1][1]);
            acc[1][2] = fmaf(a.y, b.z, acc[1][2]);
            acc[1][3] = fmaf(a.y, b.w, acc[1][3]);
            acc[2][0] = fmaf(a.z, b.x, acc[2][0]);
            acc[2][1] = fmaf(a.z, b.y, acc[2][1]);
            acc[2][2] = fmaf(a.z, b.z, acc[2][2]);
            acc[2][3] = fmaf(a.z, b.w, acc[2][3]);
            acc[3][0] = fmaf(a.w, b.x, acc[3][0]);
            acc[3][1] = fmaf(a.w, b.y, acc[3][1]);
            acc[3][2] = fmaf(a.w, b.z, acc[3][2]);
            acc[3][3] = fmaf(a.w, b.w, acc[3][3]);
        }
        __syncthreads();
    }

    const int n = n0 + tn;
    const float bias0 = b_ih[n + 0] + b_hh[n + 0];
    const float bias1 = b_ih[n + 1] + b_hh[n + 1];
    const float bias2 = b_ih[n + 2] + b_hh[n + 2];
    const float bias3 = b_ih[n + 3] + b_hh[n + 3];
#pragma unroll
    for (int i = 0; i < 4; i++) {
        float4 o;
        o.x = acc[i][0] + bias0;
        o.y = acc[i][1] + bias1;
        o.z = acc[i][2] + bias2;
        o.w = acc[i][3] + bias3;
        *(float4*)&xp[(size_t)(m0 + tm + i) * DIM + n] = o;
    }
}

// ---------------------------------------------------------------------------
// Kernel 2: RNN scan.
//  R3 post-mortem: f32x2 pointer-cast of wreg demoted it to scratch
//  (VGPR 52, VALUBusy 14%) — rule #20. This round: R1's proven structure
//  (LDS-broadcast float4 dot, one barrier/step) + W pinned via asm "+v"
//  with DIRECT wreg[i] indexing (R2-proven resident, VGPR 76) + the
//  dual-path A/B transport above: publish plain+sc1, poll sc0 with sc1
//  escalation after 16 misses. Expected mapping -> L2-latency sync
//  (~200 cyc RT vs ~700 for L3); wrong mapping -> bounded slowdown, never
//  deadlock (B-path is exactly the R1 protocol).
// ---------------------------------------------------------------------------
__global__ __launch_bounds__(512, 2)
void rnn_scan(const float4* __restrict__ Wpk, float* __restrict__ buf,
              unsigned long long* __restrict__ hpair) {
    __shared__ float hlds[RPG][DIM];        // 4 KB: h(t) rows
    __shared__ float part[2][RPG][8][64];   // 4 KB: [parity][row][ks][c]

    const int tid   = threadIdx.x;
    const int slice = blockIdx.x / GRP;   // 0..7
    const int grp   = blockIdx.x % GRP;   // 0..31
    const int c     = tid & 63;
    const int ks    = tid >> 6;           // k-slice == wave id, 0..7
    const int b0    = grp * RPG;
    const int col0  = slice * 64;
    const int hb    = ks * 16;

    unsigned long long* const hA = hpair;            // L2 fast path
    unsigned long long* const hB = hpair + 2 * SLOT; // L3 guaranteed path

    // W slice: lane c holds W[col0+c][64*ks .. 64*ks+64) as 16 float4.
    float4 wreg[16];
#pragma unroll
    for (int i = 0; i < 16; i++)
        wreg[i] = Wpk[(size_t)(hb + i) * DIM + col0 + c];
    // Pin: forbid rematerialization. Access ONLY as wreg[i] (no addr-of!).
#pragma unroll
    for (int i = 0; i < 16; i++)
        asm volatile("" : "+v"(wreg[i].x), "+v"(wreg[i].y),
                          "+v"(wreg[i].z), "+v"(wreg[i].w));

    // Each wave zeroes exactly the h region it reads -> no init barrier.
    hlds[0][tid] = 0.0f;
    hlds[1][tid] = 0.0f;
    asm volatile("" ::: "memory");

    // Lane tid polls pairs (row0,col tid) and (row1,col tid) of its group.
    const size_t pgrp = (size_t)grp * (RPG * DIM) + tid;

    const int rr = tid >> 6;   // producer row (tid < 128 only)
    const int cc = tid & 63;
    float xq = 0.0f;
    size_t bufoff = 0, puboff = 0;
    if (tid < 128) {
        bufoff = (size_t)(b0 + rr) * SEQ * DIM + col0 + cc;
        xq     = buf[bufoff];                       // xp[b][0][col]
        puboff = ((size_t)grp * RPG + rr) * DIM + col0 + cc;
    }

    for (int t = 0; t < SEQ; t++) {
        if (t > 0) {
            const size_t so = (size_t)(t & 1) * SLOT + pgrp;
            const unsigned long long* pa = hA + so;
            const unsigned long long* pb = hB + so;
            const unsigned tgt = (unsigned)t;
            unsigned long long v0, v1;
            ld2_sc0(pa, pa + DIM, v0, v1);
            int spins = 0;
            while (((unsigned)(v0 >> 32) != tgt) |
                   ((unsigned)(v1 >> 32) != tgt)) {
                if (++spins >= 16) {
                    // guaranteed-progress path (exact R1 protocol)
                    v0 = __hip_atomic_load(pb, __ATOMIC_RELAXED,
                                           __HIP_MEMORY_SCOPE_AGENT);
                    v1 = __hip_atomic_load(pb + DIM, __ATOMIC_RELAXED,
                                           __HIP_MEMORY_SCOPE_AGENT);
                    if (((unsigned)(v0 >> 32) == tgt) &
                        ((unsigned)(v1 >> 32) == tgt)) break;
                    __builtin_amdgcn_s_sleep(1);
                } else {
                    ld2_sc0(pa, pa + DIM, v0, v1);
                }
            }
            hlds[0][tid] = __uint_as_float((unsigned)v0);
            hlds[1][tid] = __uint_as_float((unsigned)v1);
            asm volatile("" ::: "memory");   // writes before broadcasts
            // no barrier: this wave reads only the region it just wrote
        }

        // Broadcast dot: p[r] = sum_j W[c][64ks+j] * h[r][64ks+j]
        float p0 = 0.f, p1 = 0.f;
        const float4* h40 = (const float4*)&hlds[0][0];
        const float4* h41 = (const float4*)&hlds[1][0];
#pragma unroll
        for (int i = 0; i < 16; i++) {
            const float4 w = wreg[i];
            const float4 a = h40[hb + i];
            const float4 b = h41[hb + i];
            p0 = fmaf(w.x, a.x, p0); p0 = fmaf(w.y, a.y, p0);
            p0 = fmaf(w.z, a.z, p0); p0 = fmaf(w.w, a.w, p0);
            p1 = fmaf(w.x, b.x, p1); p1 = fmaf(w.y, b.y, p1);
            p1 = fmaf(w.z, b.z, p1); p1 = fmaf(w.w, b.w, p1);
        }

        const int p = t & 1;
        part[p][0][ks][c] = p0;
        part[p][1][ks][c] = p1;
        __syncthreads();   // the ONLY barrier per step

        if (tid < 128) {
            float s = part[p][rr][0][cc];
#pragma unroll
            for (int k = 1; k < 8; k++) s += part[p][rr][k][cc];
            const float hn = tanhf(xq + s);
            if (t + 1 < SEQ) {
                // fused data+tag, published on BOTH paths (A first)
                const unsigned long long pv =
                    ((unsigned long long)(unsigned)(t + 1) << 32) |
                    (unsigned long long)__float_as_uint(hn);
                const size_t po = (size_t)((t + 1) & 1) * SLOT + puboff;
                st_plain(hA + po, pv);
                __hip_atomic_store(hB + po, pv, __ATOMIC_RELAXED,
                                   __HIP_MEMORY_SCOPE_AGENT);
            }
            buf[bufoff + (size_t)t * DIM] = hn;
            // prefetch next xp while other waves poll (clamped in-bounds)
            const int tn2 = (t + 1 < SEQ) ? (t + 1) : t;
            xq = buf[bufoff + (size_t)tn2 * DIM];
        }
    }
}

// ---------------------------------------------------------------------------
// Kernel 3: softmax over H (per b,t) + transpose [B][T][H] -> out [B][H][T]
// ---------------------------------------------------------------------------
__global__ __launch_bounds__(256) void softmax_T(const float* __restrict__ hid,
                                                 float* __restrict__ out) {
    __shared__ float rowmax[64];
    __shared__ float rowinv[64];
    __shared__ float tile[64][65];

    const int b   = blockIdx.x;
    const int t0  = blockIdx.y * 64;
    const int tid = threadIdx.x;
    const float* base = hid + ((size_t)b * SEQ + t0) * DIM;

    const int r = tid >> 2;
    const int p = tid & 3;

    float m = -1e30f;
#pragma unroll 4
    for (int k = 0; k < 32; k++) {
        const float4 v = *(const float4*)&base[r * DIM + ((k * 4 + p) << 2)];
        m = fmaxf(m, fmaxf(fmaxf(v.x, v.y), fmaxf(v.z, v.w)));
    }
    m = fmaxf(m, __shfl_xor(m, 1));
    m = fmaxf(m, __shfl_xor(m, 2));

    float s = 0.0f;
#pragma unroll 4
    for (int k = 0; k < 32; k++) {
        const float4 v = *(const float4*)&base[r * DIM + ((k * 4 + p) << 2)];
        s += expf(v.x - m) + expf(v.y - m) + expf(v.z - m) + expf(v.w - m);
    }
    s += __shfl_xor(s, 1);
    s += __shfl_xor(s, 2);
    if (p == 0) {
        rowmax[r] = m;
        rowinv[r] = 1.0f / s;
    }
    __syncthreads();

    for (int hc = 0; hc < 8; hc++) {
#pragma unroll
        for (int i = 0; i < 16; i++) {
            const int lin = tid + 256 * i;
            const int rrr = lin >> 6;
            const int ccc = lin & 63;
            const float v = base[rrr * DIM + hc * 64 + ccc];
            tile[ccc][rrr] = expf(v - rowmax[rrr]) * rowinv[rrr];
        }
        __syncthreads();
#pragma unroll
        for (int i = 0; i < 16; i++) {
            const int lin = tid + 256 * i;
            const int hh  = lin >> 6;
            const int tt  = lin & 63;
            out[((size_t)b * DIM + hc * 64 + hh) * SEQ + t0 + tt] = tile[hh][tt];
        }
        __syncthreads();
    }
}

// ---------------------------------------------------------------------------
extern "C" void kernel_launch(void* const* d_in, const int* in_sizes, int n_in,
                              void* d_out, int out_size, void* d_ws, size_t ws_size,
                              hipStream_t stream) {
    const int*   x    = (const int*)  d_in[0];
    const float* emb  = (const float*)d_in[1];
    const float* W_ih = (const float*)d_in[2];
    const float* W_hh = (const float*)d_in[3];
    const float* b_ih = (const float*)d_in[4];
    const float* b_hh = (const float*)d_in[5];
    float* out = (float*)d_out;

    // 64 MB scratch: xp (then hid, in place) as [B][T][H]
    float* buf = (float*)d_ws;
    // staging inside d_out (16.7M floats); all consumed before softmax_T
    // overwrites d_out (stream-ordered):
    float4* Wpk = (float4*)out;                                   // 1M floats
    unsigned long long* hpair =
        (unsigned long long*)(out + (4 << 20));   // 1 MB: A (512KB) + B (512KB)

    pack_w<<<dim3(DIM), 128, 0, stream>>>(W_hh, Wpk, hpair);
    embed_proj<<<dim3(MTOT / 64, DIM / 64), 256, 0, stream>>>(x, emb, W_ih, b_ih, b_hh, buf);
    rnn_scan<<<CSL * GRP, 512, 0, stream>>>(Wpk, buf, hpair);
    softmax_T<<<dim3(BATCH, SEQ / 64), 256, 0, stream>>>(buf, out);
}

// Round 5
// 1268.172 us; speedup vs baseline: 1.9434x; 1.9434x over previous
//
#include <hip/hip_runtime.h>
#include <cstdint>

#define BATCH 64
#define SEQ   512
#define DIM   512
#define MTOT  (BATCH*SEQ)   // 32768

// RNN decomposition: 8 column-slices x 32 batch-groups (2 rows each) = 256 wgs
#define CSL 8     // column slices (64 cols each)
#define GRP 32    // batch groups
#define RPG 2     // rows per group
#define SLOT (GRP*RPG*DIM)   // 32768 pairs per parity slot

// ---------------------------------------------------------------------------
// Kernel 0: pack W_hh [c][j] -> Wpk[jb][c] (float4 over j%4); zero tag-pairs.
// hpair must be re-zeroed EVERY launch: stale tags from a previous run
// (graph replay) would false-match targets 1..511.
// ---------------------------------------------------------------------------
__global__ __launch_bounds__(128) void pack_w(const float* __restrict__ W,
                                              float4* __restrict__ Wpk,
                                              unsigned long long* __restrict__ hpair) {
    const int c  = blockIdx.x;
    const int jb = threadIdx.x;
    const float4 v = *(const float4*)&W[(size_t)c * DIM + 4 * jb];
    Wpk[(size_t)jb * DIM + c] = v;
    // 2 slots * GRP * RPG * DIM = 65536 pairs == gridDim.x * blockDim.x
    hpair[(size_t)blockIdx.x * 128 + threadIdx.x] = 0ull;
}

// ---------------------------------------------------------------------------
// Kernel 1: fused embedding gather + input projection (NT GEMM, fp32)
// ---------------------------------------------------------------------------
__global__ __launch_bounds__(256) void embed_proj(
    const int*   __restrict__ xidx,
    const float* __restrict__ emb,
    const float* __restrict__ W_ih,
    const float* __restrict__ b_ih,
    const float* __restrict__ b_hh,
    float*       __restrict__ xp) {
    __shared__ float As[64][68];  // As[k][m]
    __shared__ float Bs[64][68];  // Bs[k][n]

    const int m0  = blockIdx.x * 64;
    const int n0  = blockIdx.y * 64;
    const int tid = threadIdx.x;

    const int lr = tid >> 4;
    const int lc = (tid & 15) << 2;

    int rows[4];
#pragma unroll
    for (int i = 0; i < 4; i++) rows[i] = xidx[m0 + lr + 16 * i];

    const int tm = (tid & 15) << 2;
    const int tn = (tid >> 4) << 2;

    float acc[4][4];
#pragma unroll
    for (int i = 0; i < 4; i++)
#pragma unroll
        for (int j = 0; j < 4; j++) acc[i][j] = 0.0f;

    for (int k0 = 0; k0 < DIM; k0 += 64) {
#pragma unroll
        for (int i = 0; i < 4; i++) {
            const int rl = lr + 16 * i;
            const float4 a = *(const float4*)&emb[(size_t)rows[i] * DIM + k0 + lc];
            As[lc + 0][rl] = a.x; As[lc + 1][rl] = a.y;
            As[lc + 2][rl] = a.z; As[lc + 3][rl] = a.w;
            const float4 b = *(const float4*)&W_ih[(size_t)(n0 + rl) * DIM + k0 + lc];
            Bs[lc + 0][rl] = b.x; Bs[lc + 1][rl] = b.y;
            Bs[lc + 2][rl] = b.z; Bs[lc + 3][rl] = b.w;
        }
        __syncthreads();
#pragma unroll 8
        for (int kk = 0; kk < 64; kk++) {
            const float4 a = *(const float4*)&As[kk][tm];
            const float4 b = *(const float4*)&Bs[kk][tn];
            acc[0][0] = fmaf(a.x, b.x, acc[0][0]);
            acc[0][1] = fmaf(a.x, b.y, acc[0][1]);
            acc[0][2] = fmaf(a.x, b.z, acc[0][2]);
            acc[0][3] = fmaf(a.x, b.w, acc[0][3]);
            acc[1][0] = fmaf(a.y, b.x, acc[1][0]);
            acc[1][1] = fmaf(a.y, b.y, acc[1][1]);
            acc[1][2] = fmaf(a.y, b.z, acc[1][2]);
            acc[1][3] = fmaf(a.y, b.w, acc[1][3]);
            acc[2][0] = fmaf(a.z, b.x, acc[2][0]);
            acc[2][1] = fmaf(a.z, b.y, acc[2][1]);
            acc[2][2] = fmaf(a.z, b.z, acc[2][2]);
            acc[2][3] = fmaf(a.z, b.w, acc[2][3]);
            acc[3][0] = fmaf(a.w, b.x, acc[3][0]);
            acc[3][1] = fmaf(a.w, b.y, acc[3][1]);
            acc[3][2] = fmaf(a.w, b.z, acc[3][2]);
            acc[3][3] = fmaf(a.w, b.w, acc[3][3]);
        }
        __syncthreads();
    }

    const int n = n0 + tn;
    const float bias0 = b_ih[n + 0] + b_hh[n + 0];
    const float bias1 = b_ih[n + 1] + b_hh[n + 1];
    const float bias2 = b_ih[n + 2] + b_hh[n + 2];
    const float bias3 = b_ih[n + 3] + b_hh[n + 3];
#pragma unroll
    for (int i = 0; i < 4; i++) {
        float4 o;
        o.x = acc[i][0] + bias0;
        o.y = acc[i][1] + bias1;
        o.z = acc[i][2] + bias2;
        o.w = acc[i][3] + bias3;
        *(float4*)&xp[(size_t)(m0 + tm + i) * DIM + n] = o;
    }
}

// ---------------------------------------------------------------------------
// Kernel 2: RNN scan.
//  R4 post-mortem: (a) plain-store/sc0-load A-path never hit -> +16 L2-spin
//  rounds per step = 2112us. Reverted to pure R1 sc1 transport. (b) VGPR=52
//  again: a function-scope asm pin lets the allocator spill wreg to scratch
//  ACROSS the loop. Fix: pin INSIDE the loop body — spilling then costs 64
//  reload+spills per iteration, so the allocator keeps wreg resident.
//  Theory: W re-stream was ~2340cy of R1's 3800cy step (128KB/wg/step from
//  L2 at ~56B/cy/CU). Residency is the single variable this round.
//  Tripwire: VGPR_Count must be >= ~110. If 52 again -> C-level pin is
//  impossible; next lever is RPG=1 (32-VGPR W slice).
// ---------------------------------------------------------------------------
__global__ __launch_bounds__(512, 2)
void rnn_scan(const float4* __restrict__ Wpk, float* __restrict__ buf,
              unsigned long long* __restrict__ hpair) {
    __shared__ float hlds[RPG][DIM];        // 4 KB: h(t) rows
    __shared__ float part[2][RPG][8][64];   // 4 KB: [parity][row][ks][c]

    const int tid   = threadIdx.x;
    const int slice = blockIdx.x / GRP;   // 0..7
    const int grp   = blockIdx.x % GRP;   // 0..31
    const int c     = tid & 63;
    const int ks    = tid >> 6;           // k-slice == wave id, 0..7
    const int b0    = grp * RPG;
    const int col0  = slice * 64;
    const int hb    = ks * 16;

    // W slice: lane c holds W[col0+c][64*ks .. 64*ks+64) as 16 float4.
    float4 wreg[16];
#pragma unroll
    for (int i = 0; i < 16; i++)
        wreg[i] = Wpk[(size_t)(hb + i) * DIM + col0 + c];

    // Each wave zeroes exactly the h region it reads -> no init barrier.
    hlds[0][tid] = 0.0f;
    hlds[1][tid] = 0.0f;
    asm volatile("" ::: "memory");

    // Lane tid polls pairs (row0,col tid) and (row1,col tid) of its group.
    const unsigned long long* const pollb =
        hpair + (size_t)grp * (RPG * DIM) + tid;

    const int rr = tid >> 6;   // producer row (tid < 128 only)
    const int cc = tid & 63;
    float xq = 0.0f;
    size_t bufoff = 0;
    unsigned long long* pubp = nullptr;
    if (tid < 128) {
        bufoff = (size_t)(b0 + rr) * SEQ * DIM + col0 + cc;
        xq     = buf[bufoff];                       // xp[b][0][col]
        pubp   = hpair + ((size_t)grp * RPG + rr) * DIM + col0 + cc;
    }

    for (int t = 0; t < SEQ; t++) {
        // IN-LOOP pin: all 64 W components must be live in VGPRs here,
        // every iteration -> allocator keeps them resident (R4 lesson:
        // a pre-loop pin allows a one-time spill to scratch).
#pragma unroll
        for (int i = 0; i < 16; i++)
            asm volatile("" : "+v"(wreg[i].x), "+v"(wreg[i].y),
                              "+v"(wreg[i].z), "+v"(wreg[i].w));

        if (t > 0) {
            const unsigned long long* bp = pollb + (size_t)(t & 1) * SLOT;
            const unsigned tgt = (unsigned)t;
            unsigned long long v0 = __hip_atomic_load(bp, __ATOMIC_RELAXED,
                                                      __HIP_MEMORY_SCOPE_AGENT);
            unsigned long long v1 = __hip_atomic_load(bp + DIM, __ATOMIC_RELAXED,
                                                      __HIP_MEMORY_SCOPE_AGENT);
            int spins = 0;
            while (((unsigned)(v0 >> 32) != tgt) |
                   ((unsigned)(v1 >> 32) != tgt)) {
                if (++spins > 16) __builtin_amdgcn_s_sleep(1);
                v0 = __hip_atomic_load(bp, __ATOMIC_RELAXED,
                                       __HIP_MEMORY_SCOPE_AGENT);
                v1 = __hip_atomic_load(bp + DIM, __ATOMIC_RELAXED,
                                       __HIP_MEMORY_SCOPE_AGENT);
            }
            hlds[0][tid] = __uint_as_float((unsigned)v0);
            hlds[1][tid] = __uint_as_float((unsigned)v1);
            asm volatile("" ::: "memory");   // writes before broadcasts
            // no barrier: this wave reads only the region it just wrote
        }

        // Broadcast dot: p[r] = sum_j W[c][64ks+j] * h[r][64ks+j]
        float p0 = 0.f, p1 = 0.f;
        const float4* h40 = (const float4*)&hlds[0][0];
        const float4* h41 = (const float4*)&hlds[1][0];
#pragma unroll
        for (int i = 0; i < 16; i++) {
            const float4 w = wreg[i];
            const float4 a = h40[hb + i];
            const float4 b = h41[hb + i];
            p0 = fmaf(w.x, a.x, p0); p0 = fmaf(w.y, a.y, p0);
            p0 = fmaf(w.z, a.z, p0); p0 = fmaf(w.w, a.w, p0);
            p1 = fmaf(w.x, b.x, p1); p1 = fmaf(w.y, b.y, p1);
            p1 = fmaf(w.z, b.z, p1); p1 = fmaf(w.w, b.w, p1);
        }

        const int p = t & 1;
        part[p][0][ks][c] = p0;
        part[p][1][ks][c] = p1;
        __syncthreads();   // the ONLY barrier per step

        if (tid < 128) {
            float s = part[p][rr][0][cc];
#pragma unroll
            for (int k = 1; k < 8; k++) s += part[p][rr][k][cc];
            const float hn = tanhf(xq + s);
            if (t + 1 < SEQ) {
                // fused data+tag: one 8B atomic, publish FIRST (critical path)
                const unsigned long long pv =
                    ((unsigned long long)(unsigned)(t + 1) << 32) |
                    (unsigned long long)__float_as_uint(hn);
                __hip_atomic_store(pubp + (size_t)((t + 1) & 1) * SLOT, pv,
                                   __ATOMIC_RELAXED, __HIP_MEMORY_SCOPE_AGENT);
            }
            buf[bufoff + (size_t)t * DIM] = hn;
            // prefetch next xp while other waves poll (clamped in-bounds)
            const int tn2 = (t + 1 < SEQ) ? (t + 1) : t;
            xq = buf[bufoff + (size_t)tn2 * DIM];
        }
    }
}

// ---------------------------------------------------------------------------
// Kernel 3: softmax over H (per b,t) + transpose [B][T][H] -> out [B][H][T]
// ---------------------------------------------------------------------------
__global__ __launch_bounds__(256) void softmax_T(const float* __restrict__ hid,
                                                 float* __restrict__ out) {
    __shared__ float rowmax[64];
    __shared__ float rowinv[64];
    __shared__ float tile[64][65];

    const int b   = blockIdx.x;
    const int t0  = blockIdx.y * 64;
    const int tid = threadIdx.x;
    const float* base = hid + ((size_t)b * SEQ + t0) * DIM;

    const int r = tid >> 2;
    const int p = tid & 3;

    float m = -1e30f;
#pragma unroll 4
    for (int k = 0; k < 32; k++) {
        const float4 v = *(const float4*)&base[r * DIM + ((k * 4 + p) << 2)];
        m = fmaxf(m, fmaxf(fmaxf(v.x, v.y), fmaxf(v.z, v.w)));
    }
    m = fmaxf(m, __shfl_xor(m, 1));
    m = fmaxf(m, __shfl_xor(m, 2));

    float s = 0.0f;
#pragma unroll 4
    for (int k = 0; k < 32; k++) {
        const float4 v = *(const float4*)&base[r * DIM + ((k * 4 + p) << 2)];
        s += expf(v.x - m) + expf(v.y - m) + expf(v.z - m) + expf(v.w - m);
    }
    s += __shfl_xor(s, 1);
    s += __shfl_xor(s, 2);
    if (p == 0) {
        rowmax[r] = m;
        rowinv[r] = 1.0f / s;
    }
    __syncthreads();

    for (int hc = 0; hc < 8; hc++) {
#pragma unroll
        for (int i = 0; i < 16; i++) {
            const int lin = tid + 256 * i;
            const int rrr = lin >> 6;
            const int ccc = lin & 63;
            const float v = base[rrr * DIM + hc * 64 + ccc];
            tile[ccc][rrr] = expf(v - rowmax[rrr]) * rowinv[rrr];
        }
        __syncthreads();
#pragma unroll
        for (int i = 0; i < 16; i++) {
            const int lin = tid + 256 * i;
            const int hh  = lin >> 6;
            const int tt  = lin & 63;
            out[((size_t)b * DIM + hc * 64 + hh) * SEQ + t0 + tt] = tile[hh][tt];
        }
        __syncthreads();
    }
}

// ---------------------------------------------------------------------------
extern "C" void kernel_launch(void* const* d_in, const int* in_sizes, int n_in,
                              void* d_out, int out_size, void* d_ws, size_t ws_size,
                              hipStream_t stream) {
    const int*   x    = (const int*)  d_in[0];
    const float* emb  = (const float*)d_in[1];
    const float* W_ih = (const float*)d_in[2];
    const float* W_hh = (const float*)d_in[3];
    const float* b_ih = (const float*)d_in[4];
    const float* b_hh = (const float*)d_in[5];
    float* out = (float*)d_out;

    // 64 MB scratch: xp (then hid, in place) as [B][T][H]
    float* buf = (float*)d_ws;
    // staging inside d_out (16.7M floats); all consumed before softmax_T
    // overwrites d_out (stream-ordered):
    float4* Wpk = (float4*)out;                                   // 1M floats
    unsigned long long* hpair =
        (unsigned long long*)(out + (4 << 20));                   // 512 KB tagged pairs

    pack_w<<<dim3(DIM), 128, 0, stream>>>(W_hh, Wpk, hpair);
    embed_proj<<<dim3(MTOT / 64, DIM / 64), 256, 0, stream>>>(x, emb, W_ih, b_ih, b_hh, buf);
    rnn_scan<<<CSL * GRP, 512, 0, stream>>>(Wpk, buf, hpair);
    softmax_T<<<dim3(BATCH, SEQ / 64), 256, 0, stream>>>(buf, out);
}